// Round 7
// baseline (556.951 us; speedup 1.0000x reference)
//
#include <hip/hip_runtime.h>
#include <hip/hip_bf16.h>

typedef unsigned short u16;
typedef __attribute__((ext_vector_type(8))) short short8;
typedef __attribute__((ext_vector_type(4))) short short4v;
typedef __attribute__((ext_vector_type(4))) float f32x4;

#define NN 50000
#define EE 400000
#define GG 256
#define MP 50048      // 391 * 128

static __device__ __forceinline__ __hip_bfloat16 f2b(float x) { return __float2bfloat16(x); }
static __device__ __forceinline__ float u16tof(u16 v) {
    unsigned int x = ((unsigned int)v) << 16;
    float f;
    __builtin_memcpy(&f, &x, 4);
    return f;
}
static __device__ __forceinline__ u16 ftou16(float x) {
    __hip_bfloat16 h = __float2bfloat16(x);
    u16 b;
    __builtin_memcpy(&b, &h, 2);
    return b;
}
static __device__ __forceinline__ void st_out(float* p, float v) { *p = v; }
static __device__ __forceinline__ void st_out(__hip_bfloat16* p, float v) { *p = f2b(v); }

// ================= phase1: weight packing + node embedding + degree counts (all independent) ===========
// blocks [0,640):          W_pqT [512 x 320] (bf16)
// blocks [640,1216):       W_bigT k<272 (Wn) and k>=528 (zero) — [272,528) owned by mm job
// blocks [1216,1472):      W_bigT rows [272,528) = (Wm2 @ Wn_s)
// blocks [1472,1491):      Wc / bc / crow (f32)
// blocks [1491,51491):     embed node n = blk-1491
// blocks [51491,53250):    edge/graph degree counting (atomics)
__global__ __launch_bounds__(256) void phase1(const float* __restrict__ Wm1,
                                              const float* __restrict__ Wn,
                                              const float* __restrict__ Wm2,
                                              const float* __restrict__ We,
                                              const float* __restrict__ be,
                                              const float* __restrict__ bm1,
                                              const float* __restrict__ bm2,
                                              __hip_bfloat16* __restrict__ WpqT,
                                              __hip_bfloat16* __restrict__ WbigT,
                                              float* __restrict__ Wc, float* __restrict__ bc,
                                              float* __restrict__ crow,
                                              const float* __restrict__ node_s,
                                              const float* __restrict__ node_v,
                                              const float* __restrict__ Ws,
                                              const float* __restrict__ bs,
                                              const float* __restrict__ Wv,
                                              const float* __restrict__ bv,
                                              __hip_bfloat16* __restrict__ XL,
                                              const int* __restrict__ ei,
                                              const int* __restrict__ batch,
                                              int* __restrict__ cnt, int* __restrict__ gcnt) {
    int blk = blockIdx.x, tid = threadIdx.x;
    if (blk < 640) {
        int idx = blk * 256 + tid;
        int c = idx / 320, k = idx - c * 320;
        float v = 0.f;
        if (c < 256) {
            if (k < 256) v = Wm1[k * 256 + c];
        } else {
            int cc = c - 256;
            if (k < 256) v = Wm1[(256 + k) * 256 + cc];
            else if (k < 272) v = Wm1[(512 + (k - 256)) * 256 + cc];
        }
        WpqT[idx] = f2b(v);
    } else if (blk < 1216) {
        int idx = (blk - 640) * 256 + tid;
        int c = idx / 576, k = idx - c * 576;
        if (k < 272) WbigT[idx] = f2b(Wn[k * 256 + c]);
        else if (k >= 528) WbigT[idx] = f2b(0.f);
    } else if (blk < 1472) {
        int r = blk - 1216, c = tid;
        float acc = 0.f;
        for (int j = 0; j < 256; ++j)
            acc += Wm2[r * 256 + j] * Wn[j * 256 + c];
        WbigT[c * 576 + 272 + r] = f2b(acc);
    } else if (blk < 1491) {
        int b = blk - 1472, c = tid;
        if (b < 17) {
            float acc = 0.f;
            for (int j = 0; j < 256; ++j)
                acc += We[b * 256 + j] * Wm1[(528 + j) * 256 + c];
            Wc[b * 256 + c] = acc;
        } else if (b == 17) {
            float acc = bm1[c];
            for (int j = 0; j < 256; ++j)
                acc += be[j] * Wm1[(528 + j) * 256 + c];
            bc[c] = acc;
        } else {
            float acc = 0.f;
            for (int j = 0; j < 256; ++j)
                acc += bm2[j] * Wn[j * 256 + c];
            crow[c] = acc;
        }
    } else if (blk < 51491) {
        // ---- embed: XL[n] = [ s(256) | vnorm(16) | meanH-slot | zero-pad k in [272,320) & [528,576) ]
        int n = blk - 1491, c = tid;
        __shared__ float ns[23];
        __shared__ float nv[12];
        if (c < 23) ns[c] = node_s[(size_t)n * 23 + c];
        if (c >= 32 && c < 44) nv[c - 32] = node_v[(size_t)n * 12 + (c - 32)];
        __syncthreads();
        float a = bs[c];
#pragma unroll
        for (int k = 0; k < 23; ++k) a += ns[k] * Ws[k * 256 + c];
        __hip_bfloat16* row = XL + (size_t)n * 576;
        row[c] = f2b(a);
        if (c < 16) {
            float b0 = bv[c];
            float vx = b0, vy = b0, vz = b0;
#pragma unroll
            for (int k = 0; k < 4; ++k) {
                float w = Wv[k * 16 + c];
                vx += nv[k * 3 + 0] * w;
                vy += nv[k * 3 + 1] * w;
                vz += nv[k * 3 + 2] * w;
            }
            row[256 + c] = f2b(sqrtf(vx * vx + vy * vy + vz * vz));
        }
        if (c < 48) {
            row[272 + c] = f2b(0.f);
            row[528 + c] = f2b(0.f);
        }
    } else {
        int b = blk - 51491;
        if (b < 1563) {
            int e = b * 256 + tid;
            if (e < EE) atomicAdd(&cnt[ei[EE + e]], 1);
        } else {
            int n = (b - 1563) * 256 + tid;
            if (n < NN) atomicAdd(&gcnt[batch[n]], 1);
        }
    }
}

// ================= CSR build =================
__global__ __launch_bounds__(256) void scan1(const int* __restrict__ cnt, int* __restrict__ rowptr,
                                             int* __restrict__ bsum) {
    int tid = threadIdx.x, i = blockIdx.x * 256 + tid;
    __shared__ int sd[256];
    int v = (i < NN) ? cnt[i] : 0;
    sd[tid] = v;
    __syncthreads();
    for (int off = 1; off < 256; off <<= 1) {
        int t = (tid >= off) ? sd[tid - off] : 0;
        __syncthreads();
        sd[tid] += t;
        __syncthreads();
    }
    if (i < NN) rowptr[i] = sd[tid] - v;
    if (tid == 255) bsum[blockIdx.x] = sd[255];
}
__global__ __launch_bounds__(256) void scan2(int* __restrict__ bsum, const int* __restrict__ gcnt,
                                             int* __restrict__ gstart) {
    int c = threadIdx.x;
    __shared__ int sd[256];
    int v = (c < 196) ? bsum[c] : 0;
    sd[c] = v;
    __syncthreads();
    for (int off = 1; off < 256; off <<= 1) {
        int t = (c >= off) ? sd[c - off] : 0;
        __syncthreads();
        sd[c] += t;
        __syncthreads();
    }
    if (c < 196) bsum[c] = sd[c] - v;
    __syncthreads();
    int g = gcnt[c];
    sd[c] = g;
    __syncthreads();
    for (int off = 1; off < 256; off <<= 1) {
        int t = (c >= off) ? sd[c - off] : 0;
        __syncthreads();
        sd[c] += t;
        __syncthreads();
    }
    gstart[c] = sd[c] - g;
    if (c == 255) gstart[256] = sd[255];
}
__global__ __launch_bounds__(256) void scan3(const int* __restrict__ cnt, const int* __restrict__ bsum,
                                             int* __restrict__ rowptr, int* __restrict__ cursor) {
    int i = blockIdx.x * 256 + threadIdx.x;
    if (i < NN) {
        int v = rowptr[i] + bsum[blockIdx.x];
        rowptr[i] = v;
        cursor[i] = v;
        if (i == NN - 1) rowptr[NN] = v + cnt[i];
    }
}
__global__ __launch_bounds__(256) void fill_csr(const int* __restrict__ ei, int* __restrict__ cursor,
                                                int* __restrict__ eid) {
    int e = blockIdx.x * 256 + threadIdx.x;
    if (e < EE) {
        int d = ei[EE + e];
        int pos = atomicAdd(&cursor[d], 1);
        eid[pos] = e;
    }
}

// ================= MFMA GEMM: C[M x Ncols] = A[M x K] * Bt[Ncols x K]^T =================
// 128x128 tile, BK=64, 4 waves 2x2; m97-style global_load_lds width-16 staging (R6-verified win).
template <typename OutT>
__global__ __launch_bounds__(256, 2) void gemm_bt(const u16* __restrict__ A, const u16* __restrict__ Bt,
                                                  OutT* __restrict__ C, int K, int lda, int Ncols) {
    __shared__ __align__(16) u16 At[128 * 64];
    __shared__ __align__(16) u16 Bs[128 * 64];
    int tid = threadIdx.x;
    long m0 = (long)blockIdx.x * 128;
    long n0 = (long)blockIdx.y * 128;
    int wid = tid >> 6, lane = tid & 63;
    int wm = wid >> 1, wn = wid & 1;
    int quad = lane >> 4, l16 = lane & 15;
    f32x4 acc[4][4] = {};
    int r0 = tid >> 3;          // 0..31
    int cc = (tid & 7) * 8;     // 0..56
    const u16* Ab = A + (m0 + r0) * lda + cc;
    const u16* Bb = Bt + (n0 + r0) * K + cc;
    for (int kt = 0; kt < K; kt += 64) {
#pragma unroll
        for (int i = 0; i < 4; ++i) {
            int row = r0 + i * 32;
            __builtin_amdgcn_global_load_lds(
                (const __attribute__((address_space(1))) void*)(Ab + (long)(i * 32) * lda + kt),
                (__attribute__((address_space(3))) void*)(&At[row * 64 + cc]), 16, 0, 0);
        }
#pragma unroll
        for (int i = 0; i < 4; ++i) {
            int row = r0 + i * 32;
            __builtin_amdgcn_global_load_lds(
                (const __attribute__((address_space(1))) void*)(Bb + (long)(i * 32) * K + kt),
                (__attribute__((address_space(3))) void*)(&Bs[row * 64 + cc]), 16, 0, 0);
        }
        __syncthreads();
#pragma unroll
        for (int kk = 0; kk < 64; kk += 32) {
            short8 af[4], bf[4];
#pragma unroll
            for (int mi = 0; mi < 4; ++mi)
                af[mi] = *(const short8*)&At[(wm * 64 + mi * 16 + l16) * 64 + kk + quad * 8];
#pragma unroll
            for (int ni = 0; ni < 4; ++ni)
                bf[ni] = *(const short8*)&Bs[(wn * 64 + ni * 16 + l16) * 64 + kk + quad * 8];
#pragma unroll
            for (int mi = 0; mi < 4; ++mi) {
#pragma unroll
                for (int ni = 0; ni < 4; ++ni)
                    acc[mi][ni] = __builtin_amdgcn_mfma_f32_16x16x32_bf16(af[mi], bf[ni], acc[mi][ni], 0, 0, 0);
            }
        }
        __syncthreads();
    }
#pragma unroll
    for (int mi = 0; mi < 4; ++mi) {
#pragma unroll
        for (int ni = 0; ni < 4; ++ni) {
            long row = m0 + wm * 64 + mi * 16 + quad * 4;
            long col = n0 + wn * 64 + ni * 16 + l16;
#pragma unroll
            for (int r = 0; r < 4; ++r)
                st_out(&C[(row + r) * Ncols + col], acc[mi][ni][r]);
        }
    }
}

// ================= edge aggregation: 1 wave/node, DEPTH-4 pipeline, split FMA chains ==============
// hidden_e = relu(P[dst] + Q[src] + edge_s[e]@Wc + bc); meanH -> XL cols [272,528).
// All (e,src) indices for a 64-edge batch staged in regs up-front -> prefetches are
// dependency-free; 4 q/es loads kept in flight. r-chain split 17 -> 8+9.
__global__ __launch_bounds__(256) void edge_agg(const u16* __restrict__ PQ,
                                                const float* __restrict__ edge_s,
                                                const int* __restrict__ ei, const int* __restrict__ eid,
                                                const int* __restrict__ rowptr, const float* __restrict__ Wc,
                                                const float* __restrict__ bc, __hip_bfloat16* __restrict__ XL) {
    int w = threadIdx.x >> 6, lane = threadIdx.x & 63;
    int n = blockIdx.x * 4 + w;
    if (n >= NN) return;
    int start = rowptr[n], deg = rowptr[n + 1] - start;
    f32x4 wc4[17];
#pragma unroll
    for (int k = 0; k < 17; ++k) wc4[k] = *(const f32x4*)&Wc[k * 256 + lane * 4];
    f32x4 bc4 = *(const f32x4*)&bc[lane * 4];
    short4v p4 = *(const short4v*)&PQ[(size_t)n * 512 + lane * 4];
    f32x4 p;
#pragma unroll
    for (int i = 0; i < 4; ++i) p[i] = u16tof((u16)p4[i]);
    f32x4 acc = {0.f, 0.f, 0.f, 0.f};
    for (int base = 0; base < deg; base += 64) {
        int m = deg - base;
        if (m > 64) m = 64;
        int ee = 0, ss = 0;   // lanes >= m keep 0 -> prefetch-safe dummy indices
        if (lane < m) {
            ee = eid[start + base + lane];
            ss = ei[ee];
        }
        short4v qb[4];
        float eb[4];
#pragma unroll
        for (int d = 0; d < 4; ++d) {
            int ed = __shfl(ee, d), sd = __shfl(ss, d);
            qb[d] = *(const short4v*)&PQ[(size_t)sd * 512 + 256 + lane * 4];
            eb[d] = (lane < 17) ? edge_s[(size_t)ed * 17 + lane] : 0.f;
        }
        for (int j = 0; j < m; j += 4) {
#pragma unroll
            for (int u = 0; u < 4; ++u) {
                int jj = j + u;
                if (jj >= m) break;     // m is wave-uniform
                short4v q = qb[u];
                float es = eb[u];
                // dependency-free prefetch of edge jj+4 (wrapped index; dummy loads are L1 hits)
                int jn = (jj + 4) & 63;
                int en = __shfl(ee, jn), sn = __shfl(ss, jn);
                qb[u] = *(const short4v*)&PQ[(size_t)sn * 512 + 256 + lane * 4];
                eb[u] = (lane < 17) ? edge_s[(size_t)en * 17 + lane] : 0.f;
                f32x4 ra = bc4;
                f32x4 rb = {0.f, 0.f, 0.f, 0.f};
#pragma unroll
                for (int k = 0; k < 8; ++k) ra += wc4[k] * __shfl(es, k);
#pragma unroll
                for (int k = 8; k < 17; ++k) rb += wc4[k] * __shfl(es, k);
#pragma unroll
                for (int i = 0; i < 4; ++i)
                    acc[i] += fmaxf(p[i] + u16tof((u16)q[i]) + ra[i] + rb[i], 0.f);
            }
        }
    }
    float inv = 1.f / fmaxf((float)deg, 1.f);
    short4v ov;
#pragma unroll
    for (int i = 0; i < 4; ++i) ov[i] = (short)ftou16(acc[i] * inv);
    *(short4v*)&XL[(size_t)n * 576 + 272 + lane * 4] = ov;
}

// ================= LayerNorm + ReLU (in place on f32 h) =================
__global__ __launch_bounds__(256) void ln_relu(float* __restrict__ h, const int* __restrict__ cnt,
                                               const float* __restrict__ bn,
                                               const float* __restrict__ crow,
                                               const float* __restrict__ gamma,
                                               const float* __restrict__ beta) {
    int n = blockIdx.x, c = threadIdx.x;
    float x = h[(size_t)n * 256 + c] + bn[c] + (cnt[n] > 0 ? crow[c] : 0.f);
    float s = x, s2 = x * x;
    for (int off = 32; off > 0; off >>= 1) {
        s += __shfl_xor(s, off, 64);
        s2 += __shfl_xor(s2, off, 64);
    }
    __shared__ float ps[4], ps2[4];
    int wid = c >> 6, lane = c & 63;
    if (lane == 0) { ps[wid] = s; ps2[wid] = s2; }
    __syncthreads();
    if (c == 0) {
        ps[0] = ps[0] + ps[1] + ps[2] + ps[3];
        ps2[0] = ps2[0] + ps2[1] + ps2[2] + ps2[3];
    }
    __syncthreads();
    float mu = ps[0] * (1.f / 256.f);
    float var = ps2[0] * (1.f / 256.f) - mu * mu;
    float y = (x - mu) * rsqrtf(var + 1e-5f) * gamma[c] + beta[c];
    h[(size_t)n * 256 + c] = fmaxf(y, 0.f);
}

// ================= global mean pool (contiguous ranges, unroll x4) =================
__global__ __launch_bounds__(256) void pool(const float* __restrict__ h,
                                            const int* __restrict__ gstart, float* __restrict__ out) {
    int g = blockIdx.x, c = threadIdx.x;
    int s = gstart[g], e = gstart[g + 1];
    float a0 = 0.f, a1 = 0.f, a2 = 0.f, a3 = 0.f;
    int n = s;
    for (; n + 3 < e; n += 4) {
        a0 += h[(size_t)n * 256 + c];
        a1 += h[(size_t)(n + 1) * 256 + c];
        a2 += h[(size_t)(n + 2) * 256 + c];
        a3 += h[(size_t)(n + 3) * 256 + c];
    }
    for (; n < e; ++n) a0 += h[(size_t)n * 256 + c];
    out[g * 256 + c] = (a0 + a1 + a2 + a3) / fmaxf((float)(e - s), 1.f);
}

extern "C" void kernel_launch(void* const* d_in, const int* in_sizes, int n_in,
                              void* d_out, int out_size, void* d_ws, size_t ws_size,
                              hipStream_t stream) {
    const float* node_s = (const float*)d_in[0];
    const float* node_v = (const float*)d_in[1];
    const float* edge_s = (const float*)d_in[2];
    const int* ei = (const int*)d_in[3];
    const int* batch = (const int*)d_in[4];
    const float* Ws = (const float*)d_in[5];
    const float* bs = (const float*)d_in[6];
    const float* Wv = (const float*)d_in[7];
    const float* bv = (const float*)d_in[8];
    const float* We = (const float*)d_in[9];
    const float* be = (const float*)d_in[10];
    const float* Wm1 = (const float*)d_in[11];
    const float* bm1 = (const float*)d_in[12];
    const float* Wm2 = (const float*)d_in[13];
    const float* bm2 = (const float*)d_in[14];
    const float* Wn = (const float*)d_in[15];
    const float* bn = (const float*)d_in[16];
    const float* gamma = (const float*)d_in[17];
    const float* beta = (const float*)d_in[18];

    char* ws = (char*)d_ws;
    size_t off = 0;
    auto take = [&](size_t n) {
        void* p = ws + off;
        off = (off + n + 255) & ~(size_t)255;
        return p;
    };
    __hip_bfloat16* XL = (__hip_bfloat16*)take((size_t)MP * 576 * 2);
    // PQ (bf16, MP*512*2 B) and h (f32, MP*256*4 B) are the same byte size; h overwrites PQ.
    __hip_bfloat16* PQ = (__hip_bfloat16*)take((size_t)MP * 512 * 2);
    float* h = (float*)PQ;
    __hip_bfloat16* WpqT = (__hip_bfloat16*)take(512 * 320 * 2);
    __hip_bfloat16* WbigT = (__hip_bfloat16*)take(256 * 576 * 2);
    float* Wc = (float*)take(17 * 256 * 4);
    float* bc = (float*)take(256 * 4);
    float* crow = (float*)take(256 * 4);
    int* cnt = (int*)take((NN + GG) * 4);
    int* gcnt = cnt + NN;
    int* rowptr = (int*)take((NN + 1) * 4);
    int* cursor = (int*)take(NN * 4);
    int* eid = (int*)take(EE * 4);
    int* bsum = (int*)take(256 * 4);
    int* gstart = (int*)take(257 * 4);

    hipMemsetAsync(cnt, 0, (NN + GG) * sizeof(int), stream);

    phase1<<<53250, 256, 0, stream>>>(Wm1, Wn, Wm2, We, be, bm1, bm2, WpqT, WbigT, Wc, bc, crow,
                                      node_s, node_v, Ws, bs, Wv, bv, XL, ei, batch, cnt, gcnt);

    scan1<<<196, 256, 0, stream>>>(cnt, rowptr, bsum);
    scan2<<<1, 256, 0, stream>>>(bsum, gcnt, gstart);
    scan3<<<196, 256, 0, stream>>>(cnt, bsum, rowptr, cursor);
    fill_csr<<<(EE + 255) / 256, 256, 0, stream>>>(ei, cursor, eid);

    // PQ = XL[:, :320] @ W_pqT^T   (K=320, lda=576, Ncols=512), bf16 out
    gemm_bt<__hip_bfloat16><<<dim3(391, 4), 256, 0, stream>>>((const u16*)XL, (const u16*)WpqT, PQ, 320, 576, 512);

    edge_agg<<<12500, 256, 0, stream>>>((const u16*)PQ, edge_s, ei, eid, rowptr, Wc, bc, XL);

    // h = XL[:, :576] @ W_bigT^T   (K=576, Ncols=256), f32 out (overwrites PQ bytes)
    gemm_bt<float><<<dim3(391, 2), 256, 0, stream>>>((const u16*)XL, (const u16*)WbigT, h, 576, 576, 256);

    ln_relu<<<NN, 256, 0, stream>>>(h, cnt, bn, crow, gamma, beta);
    pool<<<GG, 256, 0, stream>>>(h, gstart, (float*)d_out);
}

// Round 8
// 524.818 us; speedup vs baseline: 1.0612x; 1.0612x over previous
//
#include <hip/hip_runtime.h>
#include <hip/hip_bf16.h>

typedef unsigned short u16;
typedef __attribute__((ext_vector_type(8))) short short8;
typedef __attribute__((ext_vector_type(4))) short short4v;
typedef __attribute__((ext_vector_type(4))) float f32x4;

#define NN 50000
#define EE 400000
#define GG 256
#define MP 50048      // 391 * 128

static __device__ __forceinline__ __hip_bfloat16 f2b(float x) { return __float2bfloat16(x); }
static __device__ __forceinline__ float u16tof(u16 v) {
    unsigned int x = ((unsigned int)v) << 16;
    float f;
    __builtin_memcpy(&f, &x, 4);
    return f;
}
static __device__ __forceinline__ u16 ftou16(float x) {
    __hip_bfloat16 h = __float2bfloat16(x);
    u16 b;
    __builtin_memcpy(&b, &h, 2);
    return b;
}
static __device__ __forceinline__ void st_out(float* p, float v) { *p = v; }
static __device__ __forceinline__ void st_out(__hip_bfloat16* p, float v) { *p = f2b(v); }

// ================= phase1: weight packing + node embedding + degree counts (all independent) ===========
__global__ __launch_bounds__(256) void phase1(const float* __restrict__ Wm1,
                                              const float* __restrict__ Wn,
                                              const float* __restrict__ Wm2,
                                              const float* __restrict__ We,
                                              const float* __restrict__ be,
                                              const float* __restrict__ bm1,
                                              const float* __restrict__ bm2,
                                              __hip_bfloat16* __restrict__ WpqT,
                                              __hip_bfloat16* __restrict__ WbigT,
                                              float* __restrict__ Wc, float* __restrict__ bc,
                                              float* __restrict__ crow,
                                              const float* __restrict__ node_s,
                                              const float* __restrict__ node_v,
                                              const float* __restrict__ Ws,
                                              const float* __restrict__ bs,
                                              const float* __restrict__ Wv,
                                              const float* __restrict__ bv,
                                              __hip_bfloat16* __restrict__ XL,
                                              const int* __restrict__ ei,
                                              const int* __restrict__ batch,
                                              int* __restrict__ cnt, int* __restrict__ gcnt) {
    int blk = blockIdx.x, tid = threadIdx.x;
    if (blk < 640) {
        int idx = blk * 256 + tid;
        int c = idx / 320, k = idx - c * 320;
        float v = 0.f;
        if (c < 256) {
            if (k < 256) v = Wm1[k * 256 + c];
        } else {
            int cc = c - 256;
            if (k < 256) v = Wm1[(256 + k) * 256 + cc];
            else if (k < 272) v = Wm1[(512 + (k - 256)) * 256 + cc];
        }
        WpqT[idx] = f2b(v);
    } else if (blk < 1216) {
        int idx = (blk - 640) * 256 + tid;
        int c = idx / 576, k = idx - c * 576;
        if (k < 272) WbigT[idx] = f2b(Wn[k * 256 + c]);
        else if (k >= 528) WbigT[idx] = f2b(0.f);
    } else if (blk < 1472) {
        int r = blk - 1216, c = tid;
        float acc = 0.f;
        for (int j = 0; j < 256; ++j)
            acc += Wm2[r * 256 + j] * Wn[j * 256 + c];
        WbigT[c * 576 + 272 + r] = f2b(acc);
    } else if (blk < 1491) {
        int b = blk - 1472, c = tid;
        if (b < 17) {
            float acc = 0.f;
            for (int j = 0; j < 256; ++j)
                acc += We[b * 256 + j] * Wm1[(528 + j) * 256 + c];
            Wc[b * 256 + c] = acc;
        } else if (b == 17) {
            float acc = bm1[c];
            for (int j = 0; j < 256; ++j)
                acc += be[j] * Wm1[(528 + j) * 256 + c];
            bc[c] = acc;
        } else {
            float acc = 0.f;
            for (int j = 0; j < 256; ++j)
                acc += bm2[j] * Wn[j * 256 + c];
            crow[c] = acc;
        }
    } else if (blk < 51491) {
        int n = blk - 1491, c = tid;
        __shared__ float ns[23];
        __shared__ float nv[12];
        if (c < 23) ns[c] = node_s[(size_t)n * 23 + c];
        if (c >= 32 && c < 44) nv[c - 32] = node_v[(size_t)n * 12 + (c - 32)];
        __syncthreads();
        float a = bs[c];
#pragma unroll
        for (int k = 0; k < 23; ++k) a += ns[k] * Ws[k * 256 + c];
        __hip_bfloat16* row = XL + (size_t)n * 576;
        row[c] = f2b(a);
        if (c < 16) {
            float b0 = bv[c];
            float vx = b0, vy = b0, vz = b0;
#pragma unroll
            for (int k = 0; k < 4; ++k) {
                float w = Wv[k * 16 + c];
                vx += nv[k * 3 + 0] * w;
                vy += nv[k * 3 + 1] * w;
                vz += nv[k * 3 + 2] * w;
            }
            row[256 + c] = f2b(sqrtf(vx * vx + vy * vy + vz * vz));
        }
        if (c < 48) {
            row[272 + c] = f2b(0.f);
            row[528 + c] = f2b(0.f);
        }
    } else {
        int b = blk - 51491;
        if (b < 1563) {
            int e = b * 256 + tid;
            if (e < EE) atomicAdd(&cnt[ei[EE + e]], 1);
        } else {
            int n = (b - 1563) * 256 + tid;
            if (n < NN) atomicAdd(&gcnt[batch[n]], 1);
        }
    }
}

// ================= CSR build =================
__global__ __launch_bounds__(256) void scan1(const int* __restrict__ cnt, int* __restrict__ rowptr,
                                             int* __restrict__ bsum) {
    int tid = threadIdx.x, i = blockIdx.x * 256 + tid;
    __shared__ int sd[256];
    int v = (i < NN) ? cnt[i] : 0;
    sd[tid] = v;
    __syncthreads();
    for (int off = 1; off < 256; off <<= 1) {
        int t = (tid >= off) ? sd[tid - off] : 0;
        __syncthreads();
        sd[tid] += t;
        __syncthreads();
    }
    if (i < NN) rowptr[i] = sd[tid] - v;
    if (tid == 255) bsum[blockIdx.x] = sd[255];
}
__global__ __launch_bounds__(256) void scan2(int* __restrict__ bsum, const int* __restrict__ gcnt,
                                             int* __restrict__ gstart) {
    int c = threadIdx.x;
    __shared__ int sd[256];
    int v = (c < 196) ? bsum[c] : 0;
    sd[c] = v;
    __syncthreads();
    for (int off = 1; off < 256; off <<= 1) {
        int t = (c >= off) ? sd[c - off] : 0;
        __syncthreads();
        sd[c] += t;
        __syncthreads();
    }
    if (c < 196) bsum[c] = sd[c] - v;
    __syncthreads();
    int g = gcnt[c];
    sd[c] = g;
    __syncthreads();
    for (int off = 1; off < 256; off <<= 1) {
        int t = (c >= off) ? sd[c - off] : 0;
        __syncthreads();
        sd[c] += t;
        __syncthreads();
    }
    gstart[c] = sd[c] - g;
    if (c == 255) gstart[256] = sd[255];
}
__global__ __launch_bounds__(256) void scan3(const int* __restrict__ cnt, const int* __restrict__ bsum,
                                             int* __restrict__ rowptr, int* __restrict__ cursor) {
    int i = blockIdx.x * 256 + threadIdx.x;
    if (i < NN) {
        int v = rowptr[i] + bsum[blockIdx.x];
        rowptr[i] = v;
        cursor[i] = v;
        if (i == NN - 1) rowptr[NN] = v + cnt[i];
    }
}
__global__ __launch_bounds__(256) void fill_csr(const int* __restrict__ ei, int* __restrict__ cursor,
                                                int* __restrict__ eid) {
    int e = blockIdx.x * 256 + threadIdx.x;
    if (e < EE) {
        int d = ei[EE + e];
        int pos = atomicAdd(&cursor[d], 1);
        eid[pos] = e;
    }
}

// ================= MFMA GEMM: C[M x Ncols] = A[M x K] * Bt[Ncols x K]^T =================
// 128x128 tile, BK=64, 4 waves 2x2; m97-style global_load_lds width-16 staging.
template <typename OutT>
__global__ __launch_bounds__(256, 2) void gemm_bt(const u16* __restrict__ A, const u16* __restrict__ Bt,
                                                  OutT* __restrict__ C, int K, int lda, int Ncols) {
    __shared__ __align__(16) u16 At[128 * 64];
    __shared__ __align__(16) u16 Bs[128 * 64];
    int tid = threadIdx.x;
    long m0 = (long)blockIdx.x * 128;
    long n0 = (long)blockIdx.y * 128;
    int wid = tid >> 6, lane = tid & 63;
    int wm = wid >> 1, wn = wid & 1;
    int quad = lane >> 4, l16 = lane & 15;
    f32x4 acc[4][4] = {};
    int r0 = tid >> 3;          // 0..31
    int cc = (tid & 7) * 8;     // 0..56
    const u16* Ab = A + (m0 + r0) * lda + cc;
    const u16* Bb = Bt + (n0 + r0) * K + cc;
    for (int kt = 0; kt < K; kt += 64) {
#pragma unroll
        for (int i = 0; i < 4; ++i) {
            int row = r0 + i * 32;
            __builtin_amdgcn_global_load_lds(
                (const __attribute__((address_space(1))) void*)(Ab + (long)(i * 32) * lda + kt),
                (__attribute__((address_space(3))) void*)(&At[row * 64 + cc]), 16, 0, 0);
        }
#pragma unroll
        for (int i = 0; i < 4; ++i) {
            int row = r0 + i * 32;
            __builtin_amdgcn_global_load_lds(
                (const __attribute__((address_space(1))) void*)(Bb + (long)(i * 32) * K + kt),
                (__attribute__((address_space(3))) void*)(&Bs[row * 64 + cc]), 16, 0, 0);
        }
        __syncthreads();
#pragma unroll
        for (int kk = 0; kk < 64; kk += 32) {
            short8 af[4], bf[4];
#pragma unroll
            for (int mi = 0; mi < 4; ++mi)
                af[mi] = *(const short8*)&At[(wm * 64 + mi * 16 + l16) * 64 + kk + quad * 8];
#pragma unroll
            for (int ni = 0; ni < 4; ++ni)
                bf[ni] = *(const short8*)&Bs[(wn * 64 + ni * 16 + l16) * 64 + kk + quad * 8];
#pragma unroll
            for (int mi = 0; mi < 4; ++mi) {
#pragma unroll
                for (int ni = 0; ni < 4; ++ni)
                    acc[mi][ni] = __builtin_amdgcn_mfma_f32_16x16x32_bf16(af[mi], bf[ni], acc[mi][ni], 0, 0, 0);
            }
        }
        __syncthreads();
    }
#pragma unroll
    for (int mi = 0; mi < 4; ++mi) {
#pragma unroll
        for (int ni = 0; ni < 4; ++ni) {
            long row = m0 + wm * 64 + mi * 16 + quad * 4;
            long col = n0 + wn * 64 + ni * 16 + l16;
#pragma unroll
            for (int r = 0; r < 4; ++r)
                st_out(&C[(row + r) * Ncols + col], acc[mi][ni][r]);
        }
    }
}

// ================= edge aggregation: 1 wave/node, depth-2 pipeline, NO SPILLS ==============
// hidden_e = relu(P[dst]+bc + Q[src] + edge_s[e]@Wc); meanH -> XL cols [272,528).
// __launch_bounds__(256,1): wc4[17] (68 VGPR) + state must stay in registers — with the
// default bound the compiler capped at 64-72 VGPR and spilled wc4 to scratch, which was
// the R5-R7 bottleneck (VALUBusy stuck ~30% at 8 waves/CU).
__global__ __launch_bounds__(256, 1) void edge_agg(const u16* __restrict__ PQ,
                                                   const float* __restrict__ edge_s,
                                                   const int* __restrict__ ei, const int* __restrict__ eid,
                                                   const int* __restrict__ rowptr, const float* __restrict__ Wc,
                                                   const float* __restrict__ bc, __hip_bfloat16* __restrict__ XL) {
    int w = threadIdx.x >> 6, lane = threadIdx.x & 63;
    int n = blockIdx.x * 4 + w;
    if (n >= NN) return;
    int start = rowptr[n], deg = rowptr[n + 1] - start;
    f32x4 wc4[17];
#pragma unroll
    for (int k = 0; k < 17; ++k) wc4[k] = *(const f32x4*)&Wc[k * 256 + lane * 4];
    f32x4 bc4 = *(const f32x4*)&bc[lane * 4];
    short4v p4 = *(const short4v*)&PQ[(size_t)n * 512 + lane * 4];
    f32x4 pb;   // P + bc (loop-invariant)
#pragma unroll
    for (int i = 0; i < 4; ++i) pb[i] = u16tof((u16)p4[i]) + bc4[i];
    f32x4 acc = {0.f, 0.f, 0.f, 0.f};
    for (int base = 0; base < deg; base += 64) {
        int m = deg - base;
        if (m > 64) m = 64;
        int ee = 0, ss = 0;
        if (lane < m) {
            ee = eid[start + base + lane];
            ss = ei[ee];
        }
        int e0 = __shfl(ee, 0), s0 = __shfl(ss, 0);
        short4v q0 = *(const short4v*)&PQ[(size_t)s0 * 512 + 256 + lane * 4];
        float es0 = (lane < 17) ? edge_s[(size_t)e0 * 17 + lane] : 0.f;
        for (int jj = 0; jj < m; ++jj) {
            short4v q1 = q0;
            float es1 = es0;
            if (jj + 1 < m) {   // wave-uniform branch
                int e1 = __shfl(ee, jj + 1), s1 = __shfl(ss, jj + 1);
                q1 = *(const short4v*)&PQ[(size_t)s1 * 512 + 256 + lane * 4];
                es1 = (lane < 17) ? edge_s[(size_t)e1 * 17 + lane] : 0.f;
            }
            f32x4 ra = {0.f, 0.f, 0.f, 0.f};
            f32x4 rb = {0.f, 0.f, 0.f, 0.f};
#pragma unroll
            for (int k = 0; k < 8; ++k) ra += wc4[k] * __shfl(es0, k);
#pragma unroll
            for (int k = 8; k < 17; ++k) rb += wc4[k] * __shfl(es0, k);
#pragma unroll
            for (int i = 0; i < 4; ++i)
                acc[i] += fmaxf(pb[i] + u16tof((u16)q0[i]) + ra[i] + rb[i], 0.f);
            q0 = q1;
            es0 = es1;
        }
    }
    float inv = 1.f / fmaxf((float)deg, 1.f);
    short4v ov;
#pragma unroll
    for (int i = 0; i < 4; ++i) ov[i] = (short)ftou16(acc[i] * inv);
    *(short4v*)&XL[(size_t)n * 576 + 272 + lane * 4] = ov;
}

// ================= LayerNorm + ReLU (in place on f32 h) =================
__global__ __launch_bounds__(256) void ln_relu(float* __restrict__ h, const int* __restrict__ cnt,
                                               const float* __restrict__ bn,
                                               const float* __restrict__ crow,
                                               const float* __restrict__ gamma,
                                               const float* __restrict__ beta) {
    int n = blockIdx.x, c = threadIdx.x;
    float x = h[(size_t)n * 256 + c] + bn[c] + (cnt[n] > 0 ? crow[c] : 0.f);
    float s = x, s2 = x * x;
    for (int off = 32; off > 0; off >>= 1) {
        s += __shfl_xor(s, off, 64);
        s2 += __shfl_xor(s2, off, 64);
    }
    __shared__ float ps[4], ps2[4];
    int wid = c >> 6, lane = c & 63;
    if (lane == 0) { ps[wid] = s; ps2[wid] = s2; }
    __syncthreads();
    if (c == 0) {
        ps[0] = ps[0] + ps[1] + ps[2] + ps[3];
        ps2[0] = ps2[0] + ps2[1] + ps2[2] + ps2[3];
    }
    __syncthreads();
    float mu = ps[0] * (1.f / 256.f);
    float var = ps2[0] * (1.f / 256.f) - mu * mu;
    float y = (x - mu) * rsqrtf(var + 1e-5f) * gamma[c] + beta[c];
    h[(size_t)n * 256 + c] = fmaxf(y, 0.f);
}

// ================= global mean pool (contiguous ranges, unroll x4) =================
__global__ __launch_bounds__(256) void pool(const float* __restrict__ h,
                                            const int* __restrict__ gstart, float* __restrict__ out) {
    int g = blockIdx.x, c = threadIdx.x;
    int s = gstart[g], e = gstart[g + 1];
    float a0 = 0.f, a1 = 0.f, a2 = 0.f, a3 = 0.f;
    int n = s;
    for (; n + 3 < e; n += 4) {
        a0 += h[(size_t)n * 256 + c];
        a1 += h[(size_t)(n + 1) * 256 + c];
        a2 += h[(size_t)(n + 2) * 256 + c];
        a3 += h[(size_t)(n + 3) * 256 + c];
    }
    for (; n < e; ++n) a0 += h[(size_t)n * 256 + c];
    out[g * 256 + c] = (a0 + a1 + a2 + a3) / fmaxf((float)(e - s), 1.f);
}

extern "C" void kernel_launch(void* const* d_in, const int* in_sizes, int n_in,
                              void* d_out, int out_size, void* d_ws, size_t ws_size,
                              hipStream_t stream) {
    const float* node_s = (const float*)d_in[0];
    const float* node_v = (const float*)d_in[1];
    const float* edge_s = (const float*)d_in[2];
    const int* ei = (const int*)d_in[3];
    const int* batch = (const int*)d_in[4];
    const float* Ws = (const float*)d_in[5];
    const float* bs = (const float*)d_in[6];
    const float* Wv = (const float*)d_in[7];
    const float* bv = (const float*)d_in[8];
    const float* We = (const float*)d_in[9];
    const float* be = (const float*)d_in[10];
    const float* Wm1 = (const float*)d_in[11];
    const float* bm1 = (const float*)d_in[12];
    const float* Wm2 = (const float*)d_in[13];
    const float* bm2 = (const float*)d_in[14];
    const float* Wn = (const float*)d_in[15];
    const float* bn = (const float*)d_in[16];
    const float* gamma = (const float*)d_in[17];
    const float* beta = (const float*)d_in[18];

    char* ws = (char*)d_ws;
    size_t off = 0;
    auto take = [&](size_t n) {
        void* p = ws + off;
        off = (off + n + 255) & ~(size_t)255;
        return p;
    };
    __hip_bfloat16* XL = (__hip_bfloat16*)take((size_t)MP * 576 * 2);
    // PQ (bf16, MP*512*2 B) and h (f32, MP*256*4 B) are the same byte size; h overwrites PQ.
    __hip_bfloat16* PQ = (__hip_bfloat16*)take((size_t)MP * 512 * 2);
    float* h = (float*)PQ;
    __hip_bfloat16* WpqT = (__hip_bfloat16*)take(512 * 320 * 2);
    __hip_bfloat16* WbigT = (__hip_bfloat16*)take(256 * 576 * 2);
    float* Wc = (float*)take(17 * 256 * 4);
    float* bc = (float*)take(256 * 4);
    float* crow = (float*)take(256 * 4);
    int* cnt = (int*)take((NN + GG) * 4);
    int* gcnt = cnt + NN;
    int* rowptr = (int*)take((NN + 1) * 4);
    int* cursor = (int*)take(NN * 4);
    int* eid = (int*)take(EE * 4);
    int* bsum = (int*)take(256 * 4);
    int* gstart = (int*)take(257 * 4);

    hipMemsetAsync(cnt, 0, (NN + GG) * sizeof(int), stream);

    phase1<<<53250, 256, 0, stream>>>(Wm1, Wn, Wm2, We, be, bm1, bm2, WpqT, WbigT, Wc, bc, crow,
                                      node_s, node_v, Ws, bs, Wv, bv, XL, ei, batch, cnt, gcnt);

    scan1<<<196, 256, 0, stream>>>(cnt, rowptr, bsum);
    scan2<<<1, 256, 0, stream>>>(bsum, gcnt, gstart);
    scan3<<<196, 256, 0, stream>>>(cnt, bsum, rowptr, cursor);
    fill_csr<<<(EE + 255) / 256, 256, 0, stream>>>(ei, cursor, eid);

    // PQ = XL[:, :320] @ W_pqT^T   (K=320, lda=576, Ncols=512), bf16 out
    gemm_bt<__hip_bfloat16><<<dim3(391, 4), 256, 0, stream>>>((const u16*)XL, (const u16*)WpqT, PQ, 320, 576, 512);

    edge_agg<<<12500, 256, 0, stream>>>((const u16*)PQ, edge_s, ei, eid, rowptr, Wc, bc, XL);

    // h = XL[:, :576] @ W_bigT^T   (K=576, Ncols=256), f32 out (overwrites PQ bytes)
    gemm_bt<float><<<dim3(391, 2), 256, 0, stream>>>((const u16*)XL, (const u16*)WbigT, h, 576, 576, 256);

    ln_relu<<<NN, 256, 0, stream>>>(h, cnt, bn, crow, gamma, beta);
    pool<<<GG, 256, 0, stream>>>(h, gstart, (float*)d_out);
}

// Round 9
// 427.850 us; speedup vs baseline: 1.3017x; 1.2266x over previous
//
#include <hip/hip_runtime.h>
#include <hip/hip_bf16.h>

typedef unsigned short u16;
typedef __attribute__((ext_vector_type(8))) short short8;
typedef __attribute__((ext_vector_type(4))) short short4v;
typedef __attribute__((ext_vector_type(4))) float f32x4;

#define NN 50000
#define EE 400000
#define GG 256
#define MP 50048      // 391 * 128 padded rows
#define KS 64         // gemm1 K: 23 node_s + 16 vnorm + 1 ones + 24 zero
#define K2 320        // gemm2 K: 40 + 256 meanH + 24 zero

static __device__ __forceinline__ __hip_bfloat16 f2b(float x) { return __float2bfloat16(x); }
static __device__ __forceinline__ float u16tof(u16 v) {
    unsigned int x = ((unsigned int)v) << 16;
    float f;
    __builtin_memcpy(&f, &x, 4);
    return f;
}
static __device__ __forceinline__ u16 ftou16(float x) {
    __hip_bfloat16 h = __float2bfloat16(x);
    u16 b;
    __builtin_memcpy(&b, &h, 2);
    return b;
}
static __device__ __forceinline__ void st_out(float* p, float v) { *p = v; }
static __device__ __forceinline__ void st_out(__hip_bfloat16* p, float v) { *p = f2b(v); }

// ================= phase1: packing (Ws folded in) + embed-lite + degree counts =================
// blocks [0,128):        W1pqT [512 x 64]  (Ws@Wm1 folded; ones-col bias row k=39)
// blocks [128,448):      W2T   [256 x 320] (Ws@Wn_s folded, Wn_v, bias row, Wm2@Wn_s rows 40..295)
// blocks [448,467):      Wc / bc / crow (f32)
// blocks [467,12967):    embed-lite, wave-per-node: XL2[n] = [ns(23)|vnorm(16)|1|0(24)| meanH-slot(256) |0(24)]
// blocks [12967,14726):  edge/graph degree counting (atomics)
__global__ __launch_bounds__(256) void phase1(const float* __restrict__ Wm1,
                                              const float* __restrict__ Wn,
                                              const float* __restrict__ Wm2,
                                              const float* __restrict__ We,
                                              const float* __restrict__ be,
                                              const float* __restrict__ bm1,
                                              const float* __restrict__ bm2,
                                              const float* __restrict__ Ws,
                                              const float* __restrict__ bs,
                                              __hip_bfloat16* __restrict__ W1pqT,
                                              __hip_bfloat16* __restrict__ W2T,
                                              float* __restrict__ Wc, float* __restrict__ bc,
                                              float* __restrict__ crow,
                                              const float* __restrict__ node_s,
                                              const float* __restrict__ node_v,
                                              const float* __restrict__ Wv,
                                              const float* __restrict__ bv,
                                              __hip_bfloat16* __restrict__ XL2,
                                              const int* __restrict__ ei,
                                              const int* __restrict__ batch,
                                              int* __restrict__ cnt, int* __restrict__ gcnt) {
    int blk = blockIdx.x, tid = threadIdx.x;
    if (blk < 128) {
        int idx = blk * 256 + tid;          // 512*64
        int c = idx >> 6, k = idx & 63;
        float v = 0.f;
        const float* wmc = (c < 256) ? &Wm1[c] : &Wm1[256 * 256 + (c - 256)];
        if (k < 23) {
            float acc = 0.f;
            for (int j = 0; j < 256; ++j) acc += Ws[k * 256 + j] * wmc[j * 256];
            v = acc;
        } else if (k < 39) {
            if (c >= 256) v = Wm1[(512 + (k - 23)) * 256 + (c - 256)];  // vnorm rows, Q-half only
        } else if (k == 39) {
            float acc = 0.f;
            for (int j = 0; j < 256; ++j) acc += bs[j] * wmc[j * 256];
            v = acc;
        }
        W1pqT[idx] = f2b(v);
    } else if (blk < 448) {
        int idx = (blk - 128) * 256 + tid;  // 256*320
        int c = idx / 320, k = idx - c * 320;
        float v = 0.f;
        if (k < 23) {
            float acc = 0.f;
            for (int j = 0; j < 256; ++j) acc += Ws[k * 256 + j] * Wn[j * 256 + c];
            v = acc;
        } else if (k < 39) {
            v = Wn[(256 + (k - 23)) * 256 + c];
        } else if (k == 39) {
            float acc = 0.f;
            for (int j = 0; j < 256; ++j) acc += bs[j] * Wn[j * 256 + c];
            v = acc;
        } else if (k < 296) {
            int r = k - 40;
            float acc = 0.f;
            for (int j = 0; j < 256; ++j) acc += Wm2[r * 256 + j] * Wn[j * 256 + c];
            v = acc;
        }
        W2T[idx] = f2b(v);
    } else if (blk < 467) {
        int b = blk - 448, c = tid;
        if (b < 17) {
            float acc = 0.f;
            for (int j = 0; j < 256; ++j)
                acc += We[b * 256 + j] * Wm1[(528 + j) * 256 + c];
            Wc[b * 256 + c] = acc;
        } else if (b == 17) {
            float acc = bm1[c];
            for (int j = 0; j < 256; ++j)
                acc += be[j] * Wm1[(528 + j) * 256 + c];
            bc[c] = acc;
        } else {
            float acc = 0.f;
            for (int j = 0; j < 256; ++j)
                acc += bm2[j] * Wn[j * 256 + c];
            crow[c] = acc;
        }
    } else if (blk < 12967) {
        int w = tid >> 6, lane = tid & 63;
        int n = (blk - 467) * 4 + w;
        if (n < NN) {
            float lv = (lane < 23) ? node_s[(size_t)n * 23 + lane] : 0.f;
            float vv = (lane < 12) ? node_v[(size_t)n * 12 + lane] : 0.f;
            float nvk[12];
#pragma unroll
            for (int k = 0; k < 12; ++k) nvk[k] = __shfl(vv, k, 64);
            float vn = 0.f;
            if (lane < 16) {
                float b0 = bv[lane];
                float vx = b0, vy = b0, vz = b0;
#pragma unroll
                for (int k = 0; k < 4; ++k) {
                    float wv = Wv[k * 16 + lane];
                    vx += nvk[k * 3 + 0] * wv;
                    vy += nvk[k * 3 + 1] * wv;
                    vz += nvk[k * 3 + 2] * wv;
                }
                vn = sqrtf(vx * vx + vy * vy + vz * vz);
            }
            int vsrc = (lane >= 23 && lane < 39) ? (lane - 23) : 0;
            float vbc = __shfl(vn, vsrc, 64);
            float outv;
            if (lane < 23) outv = lv;
            else if (lane < 39) outv = vbc;
            else if (lane == 39) outv = 1.f;
            else outv = 0.f;   // cols 40..63: zero so gemm1 K-pad reads 0 before edge_agg overwrites
            __hip_bfloat16* row = XL2 + (size_t)n * K2;
            row[lane] = f2b(outv);
            if (lane < 24) row[296 + lane] = f2b(0.f);
        }
    } else {
        int b = blk - 12967;
        if (b < 1563) {
            int e = b * 256 + tid;
            if (e < EE) atomicAdd(&cnt[ei[EE + e]], 1);
        } else {
            int n = (b - 1563) * 256 + tid;
            if (n < NN) atomicAdd(&gcnt[batch[n]], 1);
        }
    }
}

// ================= CSR build =================
__global__ __launch_bounds__(256) void scan1(const int* __restrict__ cnt, int* __restrict__ rowptr,
                                             int* __restrict__ bsum) {
    int tid = threadIdx.x, i = blockIdx.x * 256 + tid;
    __shared__ int sd[256];
    int v = (i < NN) ? cnt[i] : 0;
    sd[tid] = v;
    __syncthreads();
    for (int off = 1; off < 256; off <<= 1) {
        int t = (tid >= off) ? sd[tid - off] : 0;
        __syncthreads();
        sd[tid] += t;
        __syncthreads();
    }
    if (i < NN) rowptr[i] = sd[tid] - v;
    if (tid == 255) bsum[blockIdx.x] = sd[255];
}
__global__ __launch_bounds__(256) void scan2(int* __restrict__ bsum) {
    int c = threadIdx.x;
    __shared__ int sd[256];
    int v = (c < 196) ? bsum[c] : 0;
    sd[c] = v;
    __syncthreads();
    for (int off = 1; off < 256; off <<= 1) {
        int t = (c >= off) ? sd[c - off] : 0;
        __syncthreads();
        sd[c] += t;
        __syncthreads();
    }
    if (c < 196) bsum[c] = sd[c] - v;
}
__global__ __launch_bounds__(256) void scan3(const int* __restrict__ cnt, const int* __restrict__ bsum,
                                             int* __restrict__ rowptr, int* __restrict__ cursor) {
    int i = blockIdx.x * 256 + threadIdx.x;
    if (i < NN) {
        int v = rowptr[i] + bsum[blockIdx.x];
        rowptr[i] = v;
        cursor[i] = v;
        if (i == NN - 1) rowptr[NN] = v + cnt[i];
    }
}
__global__ __launch_bounds__(256) void fill_csr(const int* __restrict__ ei, int* __restrict__ cursor,
                                                int* __restrict__ eid) {
    int e = blockIdx.x * 256 + threadIdx.x;
    if (e < EE) {
        int d = ei[EE + e];
        int pos = atomicAdd(&cursor[d], 1);
        eid[pos] = e;
    }
}

// ================= MFMA GEMM: C[M x Ncols] = A[M x K] * Bt[Ncols x K]^T =================
// 128x128 tile, BK=64, 4 waves 2x2; global_load_lds width-16 staging.
template <typename OutT>
__global__ __launch_bounds__(256, 2) void gemm_bt(const u16* __restrict__ A, const u16* __restrict__ Bt,
                                                  OutT* __restrict__ C, int K, int lda, int Ncols) {
    __shared__ __align__(16) u16 At[128 * 64];
    __shared__ __align__(16) u16 Bs[128 * 64];
    int tid = threadIdx.x;
    long m0 = (long)blockIdx.x * 128;
    long n0 = (long)blockIdx.y * 128;
    int wid = tid >> 6, lane = tid & 63;
    int wm = wid >> 1, wn = wid & 1;
    int quad = lane >> 4, l16 = lane & 15;
    f32x4 acc[4][4] = {};
    int r0 = tid >> 3;          // 0..31
    int cc = (tid & 7) * 8;     // 0..56
    const u16* Ab = A + (m0 + r0) * lda + cc;
    const u16* Bb = Bt + (n0 + r0) * K + cc;
    for (int kt = 0; kt < K; kt += 64) {
#pragma unroll
        for (int i = 0; i < 4; ++i) {
            int row = r0 + i * 32;
            __builtin_amdgcn_global_load_lds(
                (const __attribute__((address_space(1))) void*)(Ab + (long)(i * 32) * lda + kt),
                (__attribute__((address_space(3))) void*)(&At[row * 64 + cc]), 16, 0, 0);
        }
#pragma unroll
        for (int i = 0; i < 4; ++i) {
            int row = r0 + i * 32;
            __builtin_amdgcn_global_load_lds(
                (const __attribute__((address_space(1))) void*)(Bb + (long)(i * 32) * K + kt),
                (__attribute__((address_space(3))) void*)(&Bs[row * 64 + cc]), 16, 0, 0);
        }
        __syncthreads();
#pragma unroll
        for (int kk = 0; kk < 64; kk += 32) {
            short8 af[4], bf[4];
#pragma unroll
            for (int mi = 0; mi < 4; ++mi)
                af[mi] = *(const short8*)&At[(wm * 64 + mi * 16 + l16) * 64 + kk + quad * 8];
#pragma unroll
            for (int ni = 0; ni < 4; ++ni)
                bf[ni] = *(const short8*)&Bs[(wn * 64 + ni * 16 + l16) * 64 + kk + quad * 8];
#pragma unroll
            for (int mi = 0; mi < 4; ++mi) {
#pragma unroll
                for (int ni = 0; ni < 4; ++ni)
                    acc[mi][ni] = __builtin_amdgcn_mfma_f32_16x16x32_bf16(af[mi], bf[ni], acc[mi][ni], 0, 0, 0);
            }
        }
        __syncthreads();
    }
#pragma unroll
    for (int mi = 0; mi < 4; ++mi) {
#pragma unroll
        for (int ni = 0; ni < 4; ++ni) {
            long row = m0 + wm * 64 + mi * 16 + quad * 4;
            long col = n0 + wn * 64 + ni * 16 + l16;
#pragma unroll
            for (int r = 0; r < 4; ++r)
                st_out(&C[(row + r) * Ncols + col], acc[mi][ni][r]);
        }
    }
}

// ================= edge aggregation: 1 wave/node, depth-2 pipeline (R5/R8-verified) ==============
// hidden_e = relu(P[dst]+bc + Q[src] + edge_s[e]@Wc); meanH -> XL2 cols [40,296).
__global__ __launch_bounds__(256, 1) void edge_agg(const u16* __restrict__ PQ,
                                                   const float* __restrict__ edge_s,
                                                   const int* __restrict__ ei, const int* __restrict__ eid,
                                                   const int* __restrict__ rowptr, const float* __restrict__ Wc,
                                                   const float* __restrict__ bc, __hip_bfloat16* __restrict__ XL2) {
    int w = threadIdx.x >> 6, lane = threadIdx.x & 63;
    int n = blockIdx.x * 4 + w;
    if (n >= NN) return;
    int start = rowptr[n], deg = rowptr[n + 1] - start;
    f32x4 wc4[17];
#pragma unroll
    for (int k = 0; k < 17; ++k) wc4[k] = *(const f32x4*)&Wc[k * 256 + lane * 4];
    f32x4 bc4 = *(const f32x4*)&bc[lane * 4];
    short4v p4 = *(const short4v*)&PQ[(size_t)n * 512 + lane * 4];
    f32x4 pb;
#pragma unroll
    for (int i = 0; i < 4; ++i) pb[i] = u16tof((u16)p4[i]) + bc4[i];
    f32x4 acc = {0.f, 0.f, 0.f, 0.f};
    for (int base = 0; base < deg; base += 64) {
        int m = deg - base;
        if (m > 64) m = 64;
        int ee = 0, ss = 0;
        if (lane < m) {
            ee = eid[start + base + lane];
            ss = ei[ee];
        }
        int e0 = __shfl(ee, 0), s0 = __shfl(ss, 0);
        short4v q0 = *(const short4v*)&PQ[(size_t)s0 * 512 + 256 + lane * 4];
        float es0 = (lane < 17) ? edge_s[(size_t)e0 * 17 + lane] : 0.f;
        for (int jj = 0; jj < m; ++jj) {
            short4v q1 = q0;
            float es1 = es0;
            if (jj + 1 < m) {   // wave-uniform branch
                int e1 = __shfl(ee, jj + 1), s1 = __shfl(ss, jj + 1);
                q1 = *(const short4v*)&PQ[(size_t)s1 * 512 + 256 + lane * 4];
                es1 = (lane < 17) ? edge_s[(size_t)e1 * 17 + lane] : 0.f;
            }
            f32x4 ra = {0.f, 0.f, 0.f, 0.f};
            f32x4 rb = {0.f, 0.f, 0.f, 0.f};
#pragma unroll
            for (int k = 0; k < 8; ++k) ra += wc4[k] * __shfl(es0, k);
#pragma unroll
            for (int k = 8; k < 17; ++k) rb += wc4[k] * __shfl(es0, k);
#pragma unroll
            for (int i = 0; i < 4; ++i)
                acc[i] += fmaxf(pb[i] + u16tof((u16)q0[i]) + ra[i] + rb[i], 0.f);
            q0 = q1;
            es0 = es1;
        }
    }
    float inv = 1.f / fmaxf((float)deg, 1.f);
    short4v ov;
#pragma unroll
    for (int i = 0; i < 4; ++i) ov[i] = (short)ftou16(acc[i] * inv);
    *(short4v*)&XL2[(size_t)n * K2 + 40 + lane * 4] = ov;
}

// ================= fused LayerNorm + ReLU + pool accumulation (batch sorted) =================
// One wave handles 16 consecutive nodes; LN entirely in registers (4 ch/lane);
// per-graph partial sums accumulated locally, flushed by atomicAdd on graph change.
#define LP_CHUNK 16
__global__ __launch_bounds__(256) void ln_pool(const float* __restrict__ h, const int* __restrict__ cnt,
                                               const int* __restrict__ batch,
                                               const float* __restrict__ bn,
                                               const float* __restrict__ crow,
                                               const float* __restrict__ gamma,
                                               const float* __restrict__ beta,
                                               float* __restrict__ gsum) {
    int w = threadIdx.x >> 6, lane = threadIdx.x & 63;
    int wid = blockIdx.x * 4 + w;
    int n0 = wid * LP_CHUNK;
    if (n0 >= NN) return;
    int n1 = n0 + LP_CHUNK;
    if (n1 > NN) n1 = NN;
    f32x4 bn4 = *(const f32x4*)&bn[lane * 4];
    f32x4 cr4 = *(const f32x4*)&crow[lane * 4];
    f32x4 g4 = *(const f32x4*)&gamma[lane * 4];
    f32x4 b4 = *(const f32x4*)&beta[lane * 4];
    f32x4 acc = {0.f, 0.f, 0.f, 0.f};
    int curg = batch[n0];
    for (int n = n0; n < n1; ++n) {
        f32x4 x = *(const f32x4*)&h[(size_t)n * 256 + lane * 4];
        int dg = cnt[n];
        f32x4 xv;
#pragma unroll
        for (int i = 0; i < 4; ++i) xv[i] = x[i] + bn4[i] + (dg > 0 ? cr4[i] : 0.f);
        float s = xv[0] + xv[1] + xv[2] + xv[3];
        float s2 = xv[0] * xv[0] + xv[1] * xv[1] + xv[2] * xv[2] + xv[3] * xv[3];
        for (int off = 32; off > 0; off >>= 1) {
            s += __shfl_xor(s, off, 64);
            s2 += __shfl_xor(s2, off, 64);
        }
        float mu = s * (1.f / 256.f);
        float var = s2 * (1.f / 256.f) - mu * mu;
        float rs = rsqrtf(var + 1e-5f);
        int g = batch[n];
        if (g != curg) {
#pragma unroll
            for (int i = 0; i < 4; ++i) atomicAdd(&gsum[curg * 256 + lane * 4 + i], acc[i]);
            acc = {0.f, 0.f, 0.f, 0.f};
            curg = g;
        }
#pragma unroll
        for (int i = 0; i < 4; ++i)
            acc[i] += fmaxf((xv[i] - mu) * rs * g4[i] + b4[i], 0.f);
    }
#pragma unroll
    for (int i = 0; i < 4; ++i) atomicAdd(&gsum[curg * 256 + lane * 4 + i], acc[i]);
}

__global__ __launch_bounds__(256) void finalize(const float* __restrict__ gsum,
                                                const int* __restrict__ gcnt, float* __restrict__ out) {
    int g = blockIdx.x, c = threadIdx.x;
    out[g * 256 + c] = gsum[g * 256 + c] / fmaxf((float)gcnt[g], 1.f);
}

extern "C" void kernel_launch(void* const* d_in, const int* in_sizes, int n_in,
                              void* d_out, int out_size, void* d_ws, size_t ws_size,
                              hipStream_t stream) {
    const float* node_s = (const float*)d_in[0];
    const float* node_v = (const float*)d_in[1];
    const float* edge_s = (const float*)d_in[2];
    const int* ei = (const int*)d_in[3];
    const int* batch = (const int*)d_in[4];
    const float* Ws = (const float*)d_in[5];
    const float* bs = (const float*)d_in[6];
    const float* Wv = (const float*)d_in[7];
    const float* bv = (const float*)d_in[8];
    const float* We = (const float*)d_in[9];
    const float* be = (const float*)d_in[10];
    const float* Wm1 = (const float*)d_in[11];
    const float* bm1 = (const float*)d_in[12];
    const float* Wm2 = (const float*)d_in[13];
    const float* bm2 = (const float*)d_in[14];
    const float* Wn = (const float*)d_in[15];
    const float* bn = (const float*)d_in[16];
    const float* gamma = (const float*)d_in[17];
    const float* beta = (const float*)d_in[18];

    char* ws = (char*)d_ws;
    size_t off = 0;
    auto take = [&](size_t n) {
        void* p = ws + off;
        off = (off + n + 255) & ~(size_t)255;
        return p;
    };
    __hip_bfloat16* XL2 = (__hip_bfloat16*)take((size_t)MP * K2 * 2);   // 32 MB
    __hip_bfloat16* PQ = (__hip_bfloat16*)take((size_t)MP * 512 * 2);   // 51 MB; h (f32 MP*256) overlays
    float* h = (float*)PQ;
    __hip_bfloat16* W1pqT = (__hip_bfloat16*)take(512 * KS * 2);
    __hip_bfloat16* W2T = (__hip_bfloat16*)take(256 * K2 * 2);
    float* Wc = (float*)take(17 * 256 * 4);
    float* bc = (float*)take(256 * 4);
    float* crow = (float*)take(256 * 4);
    int* cnt = (int*)take((NN + GG) * 4 + GG * 256 * 4);   // cnt | gcnt | gsum — one zeroed region
    int* gcnt = cnt + NN;
    float* gsum = (float*)(cnt + NN + GG);
    int* rowptr = (int*)take((NN + 1) * 4);
    int* cursor = (int*)take(NN * 4);
    int* eid = (int*)take(EE * 4);
    int* bsum = (int*)take(256 * 4);

    hipMemsetAsync(cnt, 0, (NN + GG) * 4 + GG * 256 * 4, stream);

    phase1<<<14726, 256, 0, stream>>>(Wm1, Wn, Wm2, We, be, bm1, bm2, Ws, bs,
                                      W1pqT, W2T, Wc, bc, crow,
                                      node_s, node_v, Wv, bv, XL2, ei, batch, cnt, gcnt);

    scan1<<<196, 256, 0, stream>>>(cnt, rowptr, bsum);
    scan2<<<1, 256, 0, stream>>>(bsum);
    scan3<<<196, 256, 0, stream>>>(cnt, bsum, rowptr, cursor);
    fill_csr<<<(EE + 255) / 256, 256, 0, stream>>>(ei, cursor, eid);

    // PQ = XL2[:, :64] @ W1pqT^T   (K=64, lda=320, Ncols=512), bf16 out
    gemm_bt<__hip_bfloat16><<<dim3(391, 4), 256, 0, stream>>>((const u16*)XL2, (const u16*)W1pqT, PQ, KS, K2, 512);

    edge_agg<<<12500, 256, 0, stream>>>((const u16*)PQ, edge_s, ei, eid, rowptr, Wc, bc, XL2);

    // h = XL2[:, :320] @ W2T^T   (K=320, lda=320, Ncols=256), f32 out (overlays PQ bytes)
    gemm_bt<float><<<dim3(391, 2), 256, 0, stream>>>((const u16*)XL2, (const u16*)W2T, h, K2, K2, 256);

    ln_pool<<<782, 256, 0, stream>>>(h, cnt, batch, bn, crow, gamma, beta, gsum);
    finalize<<<GG, 256, 0, stream>>>(gsum, gcnt, (float*)d_out);
}